// Round 7
// baseline (136.612 us; speedup 1.0000x reference)
//
#include <hip/hip_runtime.h>
#include <hip/hip_fp16.h>

#define DEG 32
#define K_KNOTS 7
#define NINT 6  // K-1 intervals

typedef _Float16 half_t;
typedef _Float16 h2 __attribute__((ext_vector_type(2)));

// 8-byte packed edge record: unit vector (fp16 x3) + f-spline value (fp16).
union UF8 {
    uint2 u;
    struct { h2 xy; h2 zf; } h;
};

__device__ inline float fdot2(h2 a, h2 b, float c) {
#if __has_builtin(__builtin_amdgcn_fdot2)
    return __builtin_amdgcn_fdot2(a, b, c, false);
#else
    return (float)a.x * (float)b.x + (float)a.y * (float)b.y + c;
#endif
}

// Natural cubic spline with uniform knot spacing h. y[7] -> C[6] = (a,b,c,d).
__device__ inline void spline_coeffs(const float* __restrict__ y, float h, float4* C) {
    float dy[NINT];
#pragma unroll
    for (int i = 0; i < NINT; ++i) dy[i] = (y[i + 1] - y[i]) / h;
    float rhs[5];
#pragma unroll
    for (int i = 0; i < 5; ++i) rhs[i] = 6.0f * (dy[i + 1] - dy[i]);
    float cp[5], dp[5];
    float denom = 4.0f * h;
    cp[0] = h / denom;
    dp[0] = rhs[0] / denom;
#pragma unroll
    for (int i = 1; i < 5; ++i) {
        denom = 4.0f * h - h * cp[i - 1];
        cp[i] = h / denom;
        dp[i] = (rhs[i] - h * dp[i - 1]) / denom;
    }
    float M[K_KNOTS];
    M[0] = 0.0f; M[6] = 0.0f;
    M[5] = dp[4];
#pragma unroll
    for (int i = 3; i >= 0; --i) M[i + 1] = dp[i] - cp[i] * M[i + 2];
#pragma unroll
    for (int i = 0; i < NINT; ++i) {
        C[i].x = y[i];
        C[i].y = dy[i] - h * (2.0f * M[i] + M[i + 1]) * (1.0f / 6.0f);
        C[i].z = M[i] * 0.5f;
        C[i].w = (M[i + 1] - M[i]) / (6.0f * h);
    }
}

// Phase 1: per-edge. l = |r_e|, u_e = r_e/l, f_e = f(l); pack to 8 B.
// Also zeroes the histogram counters (N <= E) for the counting sort.
__global__ __launch_bounds__(256) void edge_kernel(
    const float* __restrict__ r, const float* __restrict__ fc,
    uint2* __restrict__ uf, int* __restrict__ cnt, int E, int N) {
    __shared__ float4 sF[NINT];
    if (threadIdx.x == 0) {
        float4 c[NINT];
        spline_coeffs(fc, 8.0f / 6.0f, c);  // radial knots linspace(0,8,7)
#pragma unroll
        for (int i = 0; i < NINT; ++i) sF[i] = c[i];
    }
    __syncthreads();
    int e = blockIdx.x * blockDim.x + threadIdx.x;
    if (e < N) cnt[e] = 0;
    if (e >= E) return;
    float x = r[3 * e + 0];
    float y = r[3 * e + 1];
    float z = r[3 * e + 2];
    float d = x * x + y * y + z * z;
    float rl = rsqrtf(d);
    float l = d * rl;          // |r|
    float u = l * (6.0f / 8.0f);
    int idx = (int)u;
    idx = idx < 0 ? 0 : (idx > NINT - 1 ? NINT - 1 : idx);
    float s = l - (8.0f / 6.0f) * (float)idx;
    float4 c = sF[idx];
    float f = c.x + s * (c.y + s * (c.z + s * c.w));
    UF8 q;
    q.h.xy.x = (half_t)(x * rl);
    q.h.xy.y = (half_t)(y * rl);
    q.h.zf.x = (half_t)(z * rl);
    q.h.zf.y = (half_t)f;
    uf[e] = q.u;
}

// Counting sort step 1: histogram of src atom ids. ~32 hits per counter,
// 40 KB counter array is L2-resident; device-scope atomics.
__global__ __launch_bounds__(256) void hist_kernel(
    const int* __restrict__ src, int* __restrict__ cnt, int E) {
    int e = blockIdx.x * blockDim.x + threadIdx.x;
    if (e < E) atomicAdd(&cnt[src[e]], 1);
}

// Counting sort step 2: exclusive scan over N counters -> bucket cursors.
// Single workgroup of 1024 threads; chunk-serial + Hillis-Steele LDS scan.
__global__ __launch_bounds__(1024) void scan_kernel(
    const int* __restrict__ cnt, int* __restrict__ cur, int N) {
    __shared__ int buf[2][1024];
    int tid = threadIdx.x;
    int chunk = (N + 1023) >> 10;
    int lo = tid * chunk;
    int hi = lo + chunk;
    if (lo > N) lo = N;
    if (hi > N) hi = N;
    int s = 0;
    for (int i = lo; i < hi; ++i) s += cnt[i];
    buf[0][tid] = s;
    __syncthreads();
    int pi = 0;
    for (int off = 1; off < 1024; off <<= 1) {
        int v = buf[pi][tid];
        if (tid >= off) v += buf[pi][tid - off];
        buf[pi ^ 1][tid] = v;
        pi ^= 1;
        __syncthreads();
    }
    int base = buf[pi][tid] - s;  // exclusive prefix
    for (int i = lo; i < hi; ++i) { cur[i] = base; base += cnt[i]; }
}

// Counting sort step 3: scatter edge ids into bucket order. Intra-bucket
// order is nondeterministic (atomics) but out[e] is order-independent.
__global__ __launch_bounds__(256) void scatter_kernel(
    const int* __restrict__ src, int* __restrict__ cur,
    int* __restrict__ order, int E) {
    int e = blockIdx.x * blockDim.x + threadIdx.x;
    if (e >= E) return;
    int p = atomicAdd(&cur[src[e]], 1);
    order[p] = e;
}

// Phase 2: 4 lanes per edge, edges visited in src-sorted order. Adjacent
// groups (same wave/CU) now share the same atom block -> slice-load
// addresses collapse across groups (TA same-line merge) and repeats hit L1:
// unique block gather traffic drops ~32x (R6 post-mortem: the per-edge-
// refetch of 384 B blocks was the L2/TA throughput wall). Numerics identical.
__global__ __launch_bounds__(256) void triplet_kernel(
    const uint2* __restrict__ uf, const float* __restrict__ gc,
    const int* __restrict__ src, const int* __restrict__ dst,
    const int* __restrict__ order, float* __restrict__ out, int E) {
    __shared__ float4 sG[NINT];
    if (threadIdx.x == 0) {
        float4 c[NINT];
        spline_coeffs(gc, 2.0f / 6.0f, c);  // angular knots linspace(-1,1,7)
#pragma unroll
        for (int i = 0; i < NINT; ++i) sG[i] = c[i];
    }
    __syncthreads();

    int t = blockIdx.x * blockDim.x + threadIdx.x;
    int g = t >> 2;          // 4 consecutive lanes share one edge
    int q = t & 3;           // lane's slice of the neighbor block
    if (g >= E) return;
    int e = order[g];        // src-sorted visit order

    int a = src[e];          // same addr for the 4 group lanes
    int de = dst[e];
    UF8 qe; qe.u = uf[e];
    // negated e-side unit vector, once: cos = dot(u_k, -u_e)
    uint2 neg = qe.u;
    neg.x ^= 0x80008000u;    // -(x,y)
    neg.y ^= 0x00008000u;    // -(z), keep f
    h2 ne_xy = __builtin_bit_cast(h2, neg.x);
    h2 ne_zf = __builtin_bit_cast(h2, neg.y);
    h2 ne_z0; ne_z0.x = ne_zf.x; ne_z0.y = (half_t)0.0f;
    float fe = (float)qe.h.zf.y;

    // lane's 8 records; 4 lanes at a given slot = contiguous 64 B.
    const uint4* blk = (const uint4*)(uf + (size_t)a * DEG);
    const int4* sblk = (const int4*)(src + (size_t)a * DEG);
    uint4 rq[4];
    int4 sq[2];
#pragma unroll
    for (int it = 0; it < 4; ++it) rq[it] = blk[q * 4 + it];
#pragma unroll
    for (int it = 0; it < 2; ++it) sq[it] = sblk[q * 2 + it];

    float acc = 0.0f;
#pragma unroll
    for (int rr = 0; rr < 8; ++rr) {
        uint4 qq = rq[rr >> 1];
        unsigned w0 = (rr & 1) ? qq.z : qq.x;
        unsigned w1 = (rr & 1) ? qq.w : qq.y;
        int4 sv = sq[rr >> 2];
        int s2 = (rr & 3) == 0 ? sv.x : (rr & 3) == 1 ? sv.y
               : (rr & 3) == 2 ? sv.z : sv.w;
        h2 kxy = __builtin_bit_cast(h2, w0);
        h2 kzf = __builtin_bit_cast(h2, w1);
        float cosv = fdot2(kxy, ne_xy, fdot2(kzf, ne_z0, 0.0f));
        cosv = fminf(fmaxf(cosv, -1.0f), 1.0f);
        float u = (cosv + 1.0f) * 3.0f;
        int idx = (int)u;
        idx = idx > NINT - 1 ? NINT - 1 : idx;
        float s = cosv - (-1.0f + (2.0f / 6.0f) * (float)idx);
        float4 c = sG[idx];
        float g2 = c.x + s * (c.y + s * (c.z + s * c.w));
        float fk = (float)kzf.y;
        float term = (s2 != de) ? fk * g2 : 0.0f;
        acc += term;
    }

    // reduce the 4-lane group (xor 1,2 stay within the group)
    acc += __shfl_xor(acc, 1, 64);
    acc += __shfl_xor(acc, 2, 64);
    if (q == 0) out[e] = fe * acc;   // scattered 4 B write, L2-absorbed
}

extern "C" void kernel_launch(void* const* d_in, const int* in_sizes, int n_in,
                              void* d_out, int out_size, void* d_ws, size_t ws_size,
                              hipStream_t stream) {
    const float* r   = (const float*)d_in[0];
    const float* fc  = (const float*)d_in[1];
    const float* gc  = (const float*)d_in[2];
    const int* src   = (const int*)d_in[3];
    const int* dst   = (const int*)d_in[4];
    float* out = (float*)d_out;
    int E = in_sizes[3];
    int N = E / DEG;  // dst = repeat(arange(N), DEG)

    // ws layout: uf (E*8 B) | cnt (N*4) | cur (N*4) | order (E*4)
    char* ws = (char*)d_ws;
    uint2* uf  = (uint2*)ws;
    int* cnt   = (int*)(ws + (size_t)E * 8);
    int* cur   = (int*)(ws + (size_t)E * 8 + (size_t)N * 4);
    int* order = (int*)(ws + (size_t)E * 8 + (size_t)N * 8);

    int threads = 256;
    int blocksE = (E + threads - 1) / threads;

    edge_kernel<<<blocksE, threads, 0, stream>>>(r, fc, uf, cnt, E, N);
    hist_kernel<<<blocksE, threads, 0, stream>>>(src, cnt, E);
    scan_kernel<<<1, 1024, 0, stream>>>(cnt, cur, N);
    scatter_kernel<<<blocksE, threads, 0, stream>>>(src, cur, order, E);

    long long T2 = (long long)E * 4;   // 4 lanes per edge
    int blocks2 = (int)((T2 + threads - 1) / threads);
    triplet_kernel<<<blocks2, threads, 0, stream>>>(uf, gc, src, dst, order, out, E);
}

// Round 8
// 86.898 us; speedup vs baseline: 1.5721x; 1.5721x over previous
//
#include <hip/hip_runtime.h>
#include <hip/hip_fp16.h>

#define DEG 32
#define K_KNOTS 7
#define NINT 6  // K-1 intervals

typedef _Float16 half_t;
typedef _Float16 h2 __attribute__((ext_vector_type(2)));

// 8-byte packed edge record: unit vector (fp16 x3) + f-spline value (fp16).
// 320k * 8 B = 2.56 MB -> L2-resident gather. A parallel u16 src-id array
// (640 KB) halves the mask-block gather (128 B -> 64 B per atom block).
union UF8 {
    uint2 u;
    struct { h2 xy; h2 zf; } h;
};

// Natural cubic spline with uniform knot spacing h. y[7] -> C[6] = (a,b,c,d).
// Mirrors reference: tridiag(main=4h, off=h) solve for interior 2nd derivs.
__device__ inline void spline_coeffs(const float* __restrict__ y, float h, float4* C) {
    float dy[NINT];
#pragma unroll
    for (int i = 0; i < NINT; ++i) dy[i] = (y[i + 1] - y[i]) / h;
    float rhs[5];
#pragma unroll
    for (int i = 0; i < 5; ++i) rhs[i] = 6.0f * (dy[i + 1] - dy[i]);
    float cp[5], dp[5];
    float denom = 4.0f * h;
    cp[0] = h / denom;
    dp[0] = rhs[0] / denom;
#pragma unroll
    for (int i = 1; i < 5; ++i) {
        denom = 4.0f * h - h * cp[i - 1];
        cp[i] = h / denom;
        dp[i] = (rhs[i] - h * dp[i - 1]) / denom;
    }
    float M[K_KNOTS];
    M[0] = 0.0f; M[6] = 0.0f;
    M[5] = dp[4];
#pragma unroll
    for (int i = 3; i >= 0; --i) M[i + 1] = dp[i] - cp[i] * M[i + 2];
#pragma unroll
    for (int i = 0; i < NINT; ++i) {
        C[i].x = y[i];
        C[i].y = dy[i] - h * (2.0f * M[i] + M[i + 1]) * (1.0f / 6.0f);
        C[i].z = M[i] * 0.5f;
        C[i].w = (M[i + 1] - M[i]) / (6.0f * h);
    }
}

// f-spline eval in fp32 (radial knots linspace(0,8,7)); l >= 0.
__device__ inline float eval_f(const float4* sF, float l) {
    float u = l * (6.0f / 8.0f);
    int idx = (int)u;
    idx = idx < 0 ? 0 : (idx > NINT - 1 ? NINT - 1 : idx);
    float s = l - (8.0f / 6.0f) * (float)idx;
    float4 c = sF[idx];
    return c.x + s * (c.y + s * (c.z + s * c.w));
}

// Phase 1: per-edge. l = |r_e|, u_e = r_e/l, f_e = f(l); pack to 8 B.
// Also mirrors src into a u16 array (N = 10k < 65536).
__global__ __launch_bounds__(256) void edge_kernel(
    const float* __restrict__ r, const float* __restrict__ fc,
    const int* __restrict__ src, uint2* __restrict__ uf,
    unsigned short* __restrict__ s16, int E) {
    __shared__ float4 sF[NINT];
    if (threadIdx.x == 0) {
        float4 c[NINT];
        spline_coeffs(fc, 8.0f / 6.0f, c);
#pragma unroll
        for (int i = 0; i < NINT; ++i) sF[i] = c[i];
    }
    __syncthreads();
    int e = blockIdx.x * blockDim.x + threadIdx.x;
    if (e >= E) return;
    float x = r[3 * e + 0];
    float y = r[3 * e + 1];
    float z = r[3 * e + 2];
    float d = x * x + y * y + z * z;
    float rl = rsqrtf(d);
    float l = d * rl;          // |r|
    float f = eval_f(sF, l);
    UF8 q;
    q.h.xy.x = (half_t)(x * rl);
    q.h.xy.y = (half_t)(y * rl);
    q.h.zf.x = (half_t)(z * rl);
    q.h.zf.y = (half_t)f;
    uf[e] = q.u;
    s16[e] = (unsigned short)src[e];
}

// Phase 2: 4 lanes per edge (R5 mapping; R7's sort reverted — its per-call
// preprocessing cost ~4x its gather savings). Line-touch cuts vs R6:
//   - mask block via u16 src array: 1 line -> 0.5, 2 reqs/lane -> 1
//   - e-side quantities recomputed in fp32 from r (coalesced broadcast):
//     removes the uf[e] gather and the e-side fp16 common-mode error.
// Per-edge unique L2 lines: ~3.2 -> ~2.3.
__global__ __launch_bounds__(256) void triplet_kernel(
    const uint2* __restrict__ uf, const unsigned short* __restrict__ s16,
    const float* __restrict__ r, const float* __restrict__ fc,
    const float* __restrict__ gc, const int* __restrict__ src,
    const int* __restrict__ dst, float* __restrict__ out, int E) {
    __shared__ float4 sF[NINT];
    __shared__ float4 sG[NINT];
    if (threadIdx.x == 0) {
        float4 cf[NINT], cg[NINT];
        spline_coeffs(fc, 8.0f / 6.0f, cf);   // radial knots linspace(0,8,7)
        spline_coeffs(gc, 2.0f / 6.0f, cg);   // angular knots linspace(-1,1,7)
#pragma unroll
        for (int i = 0; i < NINT; ++i) { sF[i] = cf[i]; sG[i] = cg[i]; }
    }
    __syncthreads();

    int t = blockIdx.x * blockDim.x + threadIdx.x;
    int e = t >> 2;          // 4 consecutive lanes share one edge
    int q = t & 3;           // lane's slice of the neighbor block
    if (e >= E) return;

    int a = src[e];          // broadcast within group, coalesced across wave
    int de = dst[e];
    // e-side in fp32 from r (12 B broadcast, 192 B/wave coalesced)
    float x = r[3 * e + 0];
    float y = r[3 * e + 1];
    float z = r[3 * e + 2];
    float d = x * x + y * y + z * z;
    float rl = rsqrtf(d);
    float l = d * rl;
    float fe = eval_f(sF, l);
    float nux = -x * rl, nuy = -y * rl, nuz = -z * rl;  // cos = u_k . (-u_e)

    // lane's 8 records (64 B of the 256 B uf block) + 8 u16 src ids (16 B
    // of the 64 B s16 block); 4 lanes cover each block exactly once.
    const uint4* blk = (const uint4*)(uf + (size_t)a * DEG);
    const uint4* sblk = (const uint4*)(s16 + (size_t)a * DEG);
    uint4 rq[4];
#pragma unroll
    for (int it = 0; it < 4; ++it) rq[it] = blk[q * 4 + it];
    uint4 sq = sblk[q];      // u16 records q*8 .. q*8+7

    float acc = 0.0f;
#pragma unroll
    for (int rr = 0; rr < 8; ++rr) {
        uint4 qq = rq[rr >> 1];
        unsigned w0 = (rr & 1) ? qq.z : qq.x;
        unsigned w1 = (rr & 1) ? qq.w : qq.y;
        unsigned sw = (rr >> 1) == 0 ? sq.x : (rr >> 1) == 1 ? sq.y
                    : (rr >> 1) == 2 ? sq.z : sq.w;
        int s2 = (int)((sw >> (16 * (rr & 1))) & 0xFFFFu);
        h2 kxy = __builtin_bit_cast(h2, w0);
        h2 kzf = __builtin_bit_cast(h2, w1);
        float kx = (float)kxy.x, ky = (float)kxy.y, kz = (float)kzf.x;
        float fk = (float)kzf.y;
        float cosv = kx * nux + ky * nuy + kz * nuz;
        cosv = fminf(fmaxf(cosv, -1.0f), 1.0f);
        // g(cos): cos in [-1,1] -> u in [0,6]; trunc == floor (u >= 0)
        float u = (cosv + 1.0f) * 3.0f;
        int idx = (int)u;
        idx = idx > NINT - 1 ? NINT - 1 : idx;
        float s = cosv - (-1.0f + (2.0f / 6.0f) * (float)idx);
        float4 c = sG[idx];
        float g2 = c.x + s * (c.y + s * (c.z + s * c.w));
        float term = (s2 != de) ? fk * g2 : 0.0f;
        acc += term;
    }

    // reduce the 4-lane group (xor 1,2 stay within the group)
    acc += __shfl_xor(acc, 1, 64);
    acc += __shfl_xor(acc, 2, 64);
    if (q == 0) out[e] = fe * acc;
}

extern "C" void kernel_launch(void* const* d_in, const int* in_sizes, int n_in,
                              void* d_out, int out_size, void* d_ws, size_t ws_size,
                              hipStream_t stream) {
    const float* r   = (const float*)d_in[0];
    const float* fc  = (const float*)d_in[1];
    const float* gc  = (const float*)d_in[2];
    const int* src   = (const int*)d_in[3];
    const int* dst   = (const int*)d_in[4];
    float* out = (float*)d_out;
    int E = in_sizes[3];

    // ws layout: uf (E*8 B) | s16 (E*2 B)
    char* ws = (char*)d_ws;
    uint2* uf = (uint2*)ws;
    unsigned short* s16 = (unsigned short*)(ws + (size_t)E * 8);

    int threads = 256;
    int blocks1 = (E + threads - 1) / threads;
    edge_kernel<<<blocks1, threads, 0, stream>>>(r, fc, src, uf, s16, E);

    long long T2 = (long long)E * 4;   // 4 lanes per edge
    int blocks2 = (int)((T2 + threads - 1) / threads);
    triplet_kernel<<<blocks2, threads, 0, stream>>>(uf, s16, r, fc, gc, src,
                                                    dst, out, E);
}

// Round 9
// 82.849 us; speedup vs baseline: 1.6489x; 1.0489x over previous
//
#include <hip/hip_runtime.h>
#include <hip/hip_fp16.h>

#define DEG 32
#define K_KNOTS 7
#define NINT 6  // K-1 intervals

typedef _Float16 half_t;
typedef _Float16 h2 __attribute__((ext_vector_type(2)));

// 8-byte packed edge record: unit vector (fp16 x3) + f-spline value (fp16).
// 320k * 8 B = 2.56 MB -> L2-resident gather. Parallel u16 src-id array
// (640 KB) halves the mask-block gather (128 B -> 64 B per atom block).
union UF8 {
    uint2 u;
    struct { h2 xy; h2 zf; } h;
};

__device__ inline float fdot2(h2 a, h2 b, float c) {
#if __has_builtin(__builtin_amdgcn_fdot2)
    return __builtin_amdgcn_fdot2(a, b, c, false);
#else
    return (float)a.x * (float)b.x + (float)a.y * (float)b.y + c;
#endif
}

// Natural cubic spline with uniform knot spacing h. y[7] -> C[6] = (a,b,c,d).
// Mirrors reference: tridiag(main=4h, off=h) solve for interior 2nd derivs.
__device__ inline void spline_coeffs(const float* __restrict__ y, float h, float4* C) {
    float dy[NINT];
#pragma unroll
    for (int i = 0; i < NINT; ++i) dy[i] = (y[i + 1] - y[i]) / h;
    float rhs[5];
#pragma unroll
    for (int i = 0; i < 5; ++i) rhs[i] = 6.0f * (dy[i + 1] - dy[i]);
    float cp[5], dp[5];
    float denom = 4.0f * h;
    cp[0] = h / denom;
    dp[0] = rhs[0] / denom;
#pragma unroll
    for (int i = 1; i < 5; ++i) {
        denom = 4.0f * h - h * cp[i - 1];
        cp[i] = h / denom;
        dp[i] = (rhs[i] - h * dp[i - 1]) / denom;
    }
    float M[K_KNOTS];
    M[0] = 0.0f; M[6] = 0.0f;
    M[5] = dp[4];
#pragma unroll
    for (int i = 3; i >= 0; --i) M[i + 1] = dp[i] - cp[i] * M[i + 2];
#pragma unroll
    for (int i = 0; i < NINT; ++i) {
        C[i].x = y[i];
        C[i].y = dy[i] - h * (2.0f * M[i] + M[i + 1]) * (1.0f / 6.0f);
        C[i].z = M[i] * 0.5f;
        C[i].w = (M[i + 1] - M[i]) / (6.0f * h);
    }
}

// Phase 1: per-edge. l = |r_e|, u_e = r_e/l, f_e = f(l); pack to 8 B.
// Also mirrors src into a u16 array (N = 10k < 65536).
__global__ __launch_bounds__(256) void edge_kernel(
    const float* __restrict__ r, const float* __restrict__ fc,
    const int* __restrict__ src, uint2* __restrict__ uf,
    unsigned short* __restrict__ s16, int E) {
    __shared__ float4 sF[NINT];
    if (threadIdx.x == 0) {
        float4 c[NINT];
        spline_coeffs(fc, 8.0f / 6.0f, c);  // radial knots linspace(0,8,7)
#pragma unroll
        for (int i = 0; i < NINT; ++i) sF[i] = c[i];
    }
    __syncthreads();
    int e = blockIdx.x * blockDim.x + threadIdx.x;
    if (e >= E) return;
    float x = r[3 * e + 0];
    float y = r[3 * e + 1];
    float z = r[3 * e + 2];
    float d = x * x + y * y + z * z;
    float rl = rsqrtf(d);
    float l = d * rl;          // |r|
    float u = l * (6.0f / 8.0f);
    int idx = (int)u;
    idx = idx < 0 ? 0 : (idx > NINT - 1 ? NINT - 1 : idx);
    float s = l - (8.0f / 6.0f) * (float)idx;
    float4 c = sF[idx];
    float f = c.x + s * (c.y + s * (c.z + s * c.w));
    UF8 q;
    q.h.xy.x = (half_t)(x * rl);
    q.h.xy.y = (half_t)(y * rl);
    q.h.zf.x = (half_t)(z * rl);
    q.h.zf.y = (half_t)f;
    uf[e] = q.u;
    s16[e] = (unsigned short)src[e];
}

// Phase 2: exact R5 structure (fdot2 fp16 path, fp16 e-side from uf[e],
// 4 lanes/edge) with ONE change vs R5: the neighbor mask ids come from the
// u16 s16 array (1 uint4/lane = 16 B) instead of src (2 int4 = 32 B).
// Per edge: gathered bytes 384->320, unique L2 lines 3.2->2.6, VMEM
// instrs/lane 7->6, VALU unchanged. (R8 post-mortem: fp32 e-side recompute
// traded lines for VALU at a net loss; this keeps R5's instruction mix.)
__global__ __launch_bounds__(256) void triplet_kernel(
    const uint2* __restrict__ uf, const unsigned short* __restrict__ s16,
    const float* __restrict__ gc, const int* __restrict__ src,
    const int* __restrict__ dst, float* __restrict__ out, int E) {
    __shared__ float4 sG[NINT];
    if (threadIdx.x == 0) {
        float4 c[NINT];
        spline_coeffs(gc, 2.0f / 6.0f, c);  // angular knots linspace(-1,1,7)
#pragma unroll
        for (int i = 0; i < NINT; ++i) sG[i] = c[i];
    }
    __syncthreads();

    int t = blockIdx.x * blockDim.x + threadIdx.x;
    int e = t >> 2;          // 4 consecutive lanes share one edge
    int q = t & 3;           // lane's slice of the neighbor block
    if (e >= E) return;

    int a = src[e];          // same addr for the 4 group lanes
    int de = dst[e];
    UF8 qe; qe.u = uf[e];
    // negated e-side unit vector, once: cos = dot(u_k, -u_e)
    uint2 neg = qe.u;
    neg.x ^= 0x80008000u;    // -(x,y)
    neg.y ^= 0x00008000u;    // -(z), keep f
    h2 ne_xy = __builtin_bit_cast(h2, neg.x);
    h2 ne_zf = __builtin_bit_cast(h2, neg.y);
    h2 ne_z0; ne_z0.x = ne_zf.x; ne_z0.y = (half_t)0.0f;
    float fe = (float)qe.h.zf.y;

    // lane's 8 records (64 B of the 256 B uf block) + 8 u16 ids (16 B of
    // the 64 B s16 block); 4 lanes cover each block exactly once.
    const uint4* blk = (const uint4*)(uf + (size_t)a * DEG);
    const uint4* sblk = (const uint4*)(s16 + (size_t)a * DEG);
    uint4 rq[4];
#pragma unroll
    for (int it = 0; it < 4; ++it) rq[it] = blk[q * 4 + it];
    uint4 sq = sblk[q];      // u16 records q*8 .. q*8+7

    float acc = 0.0f;
#pragma unroll
    for (int rr = 0; rr < 8; ++rr) {
        uint4 qq = rq[rr >> 1];
        unsigned w0 = (rr & 1) ? qq.z : qq.x;
        unsigned w1 = (rr & 1) ? qq.w : qq.y;
        unsigned sw = (rr >> 1) == 0 ? sq.x : (rr >> 1) == 1 ? sq.y
                    : (rr >> 1) == 2 ? sq.z : sq.w;
        int s2 = (int)((sw >> (16 * (rr & 1))) & 0xFFFFu);
        h2 kxy = __builtin_bit_cast(h2, w0);
        h2 kzf = __builtin_bit_cast(h2, w1);
        float cosv = fdot2(kxy, ne_xy, fdot2(kzf, ne_z0, 0.0f));
        cosv = fminf(fmaxf(cosv, -1.0f), 1.0f);
        // g(cos): cos in [-1,1] -> u in [0,6]; trunc == floor (u >= 0)
        float u = (cosv + 1.0f) * 3.0f;
        int idx = (int)u;
        idx = idx > NINT - 1 ? NINT - 1 : idx;
        float s = cosv - (-1.0f + (2.0f / 6.0f) * (float)idx);
        float4 c = sG[idx];
        float g2 = c.x + s * (c.y + s * (c.z + s * c.w));
        float fk = (float)kzf.y;
        float term = (s2 != de) ? fk * g2 : 0.0f;
        acc += term;
    }

    // reduce the 4-lane group (xor 1,2 stay within the group)
    acc += __shfl_xor(acc, 1, 64);
    acc += __shfl_xor(acc, 2, 64);
    if (q == 0) out[e] = fe * acc;
}

extern "C" void kernel_launch(void* const* d_in, const int* in_sizes, int n_in,
                              void* d_out, int out_size, void* d_ws, size_t ws_size,
                              hipStream_t stream) {
    const float* r   = (const float*)d_in[0];
    const float* fc  = (const float*)d_in[1];
    const float* gc  = (const float*)d_in[2];
    const int* src   = (const int*)d_in[3];
    const int* dst   = (const int*)d_in[4];
    float* out = (float*)d_out;
    int E = in_sizes[3];

    // ws layout: uf (E*8 B) | s16 (E*2 B)
    char* ws = (char*)d_ws;
    uint2* uf = (uint2*)ws;
    unsigned short* s16 = (unsigned short*)(ws + (size_t)E * 8);

    int threads = 256;
    int blocks1 = (E + threads - 1) / threads;
    edge_kernel<<<blocks1, threads, 0, stream>>>(r, fc, src, uf, s16, E);

    long long T2 = (long long)E * 4;   // 4 lanes per edge
    int blocks2 = (int)((T2 + threads - 1) / threads);
    triplet_kernel<<<blocks2, threads, 0, stream>>>(uf, s16, gc, src, dst, out, E);
}

// Round 10
// 82.572 us; speedup vs baseline: 1.6545x; 1.0034x over previous
//
#include <hip/hip_runtime.h>
#include <hip/hip_fp16.h>

#define DEG 32
#define K_KNOTS 7
#define NINT 6  // K-1 intervals

typedef _Float16 half_t;
typedef _Float16 h2 __attribute__((ext_vector_type(2)));

// 8-byte packed edge record: unit vector (fp16 x3) + f-spline value (fp16),
// stored as two half2: (x,y) and (z,f). 320k edges * 8 B = 2.56 MB keeps the
// phase-2 random gather L2-resident (FETCH ~19 MB steady since R3).
//
// FINAL CONFIG (= R5, best measured 81.5 us total). Probed and rejected:
//   R6: 2 edges/group (2x MLP)            -> neutral (not latency-bound)
//   R7: src-sorted visit order (32x reuse)-> +55 us (per-call sort >> savings)
//   R8: fp32 e-side + u16 mask (-lines,+VALU) -> +5 us (VALU-sensitive)
//   R9: u16 mask only (-20% lines)        -> neutral (not line-limited)
// Plateau: balanced TA/L1-miss serialization on an irreducible random
// 320 B/edge gather; VALU floor ~2.3 us, line floor ~3 us, measured ~15 us.
union UF8 {
    uint2 u;
    struct { h2 xy; h2 zf; } h;
};

__device__ inline float fdot2(h2 a, h2 b, float c) {
#if __has_builtin(__builtin_amdgcn_fdot2)
    return __builtin_amdgcn_fdot2(a, b, c, false);
#else
    return (float)a.x * (float)b.x + (float)a.y * (float)b.y + c;
#endif
}

// Natural cubic spline with uniform knot spacing h. y[7] -> C[6] = (a,b,c,d).
// Mirrors reference: tridiag(main=4h, off=h) solve for interior 2nd derivs.
__device__ inline void spline_coeffs(const float* __restrict__ y, float h, float4* C) {
    float dy[NINT];
#pragma unroll
    for (int i = 0; i < NINT; ++i) dy[i] = (y[i + 1] - y[i]) / h;
    float rhs[5];
#pragma unroll
    for (int i = 0; i < 5; ++i) rhs[i] = 6.0f * (dy[i + 1] - dy[i]);
    float cp[5], dp[5];
    float denom = 4.0f * h;
    cp[0] = h / denom;
    dp[0] = rhs[0] / denom;
#pragma unroll
    for (int i = 1; i < 5; ++i) {
        denom = 4.0f * h - h * cp[i - 1];
        cp[i] = h / denom;
        dp[i] = (rhs[i] - h * dp[i - 1]) / denom;
    }
    float M[K_KNOTS];
    M[0] = 0.0f; M[6] = 0.0f;
    M[5] = dp[4];
#pragma unroll
    for (int i = 3; i >= 0; --i) M[i + 1] = dp[i] - cp[i] * M[i + 2];
#pragma unroll
    for (int i = 0; i < NINT; ++i) {
        C[i].x = y[i];
        C[i].y = dy[i] - h * (2.0f * M[i] + M[i + 1]) * (1.0f / 6.0f);
        C[i].z = M[i] * 0.5f;
        C[i].w = (M[i + 1] - M[i]) / (6.0f * h);
    }
}

// Phase 1: per-edge. l = |r_e|, u_e = r_e/l, f_e = f(l); pack to 8 B.
__global__ __launch_bounds__(256) void edge_kernel(
    const float* __restrict__ r, const float* __restrict__ fc,
    uint2* __restrict__ uf, int E) {
    __shared__ float4 sF[NINT];
    if (threadIdx.x == 0) {
        float4 c[NINT];
        spline_coeffs(fc, 8.0f / 6.0f, c);  // radial knots linspace(0,8,7)
#pragma unroll
        for (int i = 0; i < NINT; ++i) sF[i] = c[i];
    }
    __syncthreads();
    int e = blockIdx.x * blockDim.x + threadIdx.x;
    if (e >= E) return;
    float x = r[3 * e + 0];
    float y = r[3 * e + 1];
    float z = r[3 * e + 2];
    float d = x * x + y * y + z * z;
    float rl = rsqrtf(d);
    float l = d * rl;          // |r|
    // f(l): l >= 0 so trunc == floor; idx clamp handles extrapolation (l > 8)
    float u = l * (6.0f / 8.0f);
    int idx = (int)u;
    idx = idx < 0 ? 0 : (idx > NINT - 1 ? NINT - 1 : idx);
    float s = l - (8.0f / 6.0f) * (float)idx;
    float4 c = sF[idx];
    float f = c.x + s * (c.y + s * (c.z + s * c.w));
    UF8 q;
    q.h.xy.x = (half_t)(x * rl);
    q.h.xy.y = (half_t)(y * rl);
    q.h.zf.x = (half_t)(z * rl);
    q.h.zf.y = (half_t)f;
    uf[e] = q.u;
}

// Phase 2: FOUR lanes per edge. Lane group q=0..3 of edge e loads 64 B of
// the 256 B neighbor block -> for a fixed unroll slot the 4 lanes cover one
// contiguous cache line; each lane serially accumulates its 8 triplets
// (fdot2: fp16 products exact in f32), then a 2-round shfl reduces the group
// and the wave-uniform f_e factor is applied once.
__global__ __launch_bounds__(256) void triplet_kernel(
    const uint2* __restrict__ uf, const float* __restrict__ gc,
    const int* __restrict__ src, const int* __restrict__ dst,
    float* __restrict__ out, int E) {
    __shared__ float4 sG[NINT];
    if (threadIdx.x == 0) {
        float4 c[NINT];
        spline_coeffs(gc, 2.0f / 6.0f, c);  // angular knots linspace(-1,1,7)
#pragma unroll
        for (int i = 0; i < NINT; ++i) sG[i] = c[i];
    }
    __syncthreads();

    int t = blockIdx.x * blockDim.x + threadIdx.x;
    int e = t >> 2;          // 4 consecutive lanes share one edge
    int q = t & 3;           // lane's slice of the neighbor block
    if (e >= E) return;

    int a = src[e];          // same addr for the 4 group lanes
    int de = dst[e];
    UF8 qe; qe.u = uf[e];
    // negated e-side unit vector, once: cos = dot(u_k, -u_e)
    uint2 neg = qe.u;
    neg.x ^= 0x80008000u;    // -(x,y)
    neg.y ^= 0x00008000u;    // -(z), keep f
    h2 ne_xy = __builtin_bit_cast(h2, neg.x);
    h2 ne_zf = __builtin_bit_cast(h2, neg.y);
    h2 ne_z0; ne_z0.x = ne_zf.x; ne_z0.y = (half_t)0.0f;
    float fe = (float)qe.h.zf.y;

    // lane's 8 records: uint4 slot it covers records q*8+2it, q*8+2it+1;
    // 4 lanes at slot it = contiguous 64 B.
    const uint4* blk = (const uint4*)(uf + (size_t)a * DEG);
    const int4* sblk = (const int4*)(src + (size_t)a * DEG);
    uint4 rq[4];
    int4 sq[2];
#pragma unroll
    for (int it = 0; it < 4; ++it) rq[it] = blk[q * 4 + it];
#pragma unroll
    for (int it = 0; it < 2; ++it) sq[it] = sblk[q * 2 + it];

    float acc = 0.0f;
#pragma unroll
    for (int rr = 0; rr < 8; ++rr) {
        uint4 qq = rq[rr >> 1];
        unsigned w0 = (rr & 1) ? qq.z : qq.x;
        unsigned w1 = (rr & 1) ? qq.w : qq.y;
        int4 sv = sq[rr >> 2];
        int s2 = (rr & 3) == 0 ? sv.x : (rr & 3) == 1 ? sv.y
               : (rr & 3) == 2 ? sv.z : sv.w;
        h2 kxy = __builtin_bit_cast(h2, w0);
        h2 kzf = __builtin_bit_cast(h2, w1);
        float cosv = fdot2(kxy, ne_xy, fdot2(kzf, ne_z0, 0.0f));
        cosv = fminf(fmaxf(cosv, -1.0f), 1.0f);
        // g(cos): cos in [-1,1] -> u in [0,6]; trunc == floor (u >= 0)
        float u = (cosv + 1.0f) * 3.0f;
        int idx = (int)u;
        idx = idx > NINT - 1 ? NINT - 1 : idx;
        float s = cosv - (-1.0f + (2.0f / 6.0f) * (float)idx);
        float4 c = sG[idx];
        float g = c.x + s * (c.y + s * (c.z + s * c.w));
        float fk = (float)kzf.y;
        float term = (s2 != de) ? fk * g : 0.0f;
        acc += term;
    }

    // reduce the 4-lane group (xor 1,2 stay within the group)
    acc += __shfl_xor(acc, 1, 64);
    acc += __shfl_xor(acc, 2, 64);
    if (q == 0) out[e] = fe * acc;
}

extern "C" void kernel_launch(void* const* d_in, const int* in_sizes, int n_in,
                              void* d_out, int out_size, void* d_ws, size_t ws_size,
                              hipStream_t stream) {
    const float* r   = (const float*)d_in[0];
    const float* fc  = (const float*)d_in[1];
    const float* gc  = (const float*)d_in[2];
    const int* src   = (const int*)d_in[3];
    const int* dst   = (const int*)d_in[4];
    float* out = (float*)d_out;
    int E = in_sizes[3];

    uint2* uf = (uint2*)d_ws;  // E * 8 bytes

    int threads = 256;
    int blocks1 = (E + threads - 1) / threads;
    edge_kernel<<<blocks1, threads, 0, stream>>>(r, fc, uf, E);

    long long T2 = (long long)E * 4;   // 4 lanes per edge
    int blocks2 = (int)((T2 + threads - 1) / threads);
    triplet_kernel<<<blocks2, threads, 0, stream>>>(uf, gc, src, dst, out, E);
}